// Round 1
// baseline (2609.565 us; speedup 1.0000x reference)
//
#include <hip/hip_runtime.h>
#include <math.h>

#define N_NODES 50000
#define E_EDGES 800000
#define D 128          // NODE_DIM
#define HID 128        // HIDDEN
#define NB 32          // NBASIS
#define EB 32          // edges per block
#define NBK 32         // nodes per block

__device__ __forceinline__ float silu_f(float x) {
    return x / (1.0f + __expf(-x));
}

// ---------------------------------------------------------------------------
// Edge kernel: message MLP + coord head + atomic scatter aggregation
// block = 256 threads, EB=32 edges. Thread (t): cg=t&31 -> 4 output channels
// c0=4*cg; eg=t>>5 -> 4 edges eg*4..eg*4+3. acc[4][4] register tile.
// ---------------------------------------------------------------------------
__global__ __launch_bounds__(256, 2) void egnn_edge(
    const float* __restrict__ h, const float* __restrict__ pos,
    const int* __restrict__ ei,
    const float* __restrict__ mw1, const float* __restrict__ mb1,
    const float* __restrict__ mw2, const float* __restrict__ mb2,
    const float* __restrict__ cw1, const float* __restrict__ cb1,
    const float* __restrict__ cw2, const float* __restrict__ cb2,
    float* __restrict__ aggr_msgs, float* __restrict__ aggr_coord)
{
    __shared__ float s_in[EB][2 * D + NB];   // msg_in, 288 per edge
    __shared__ float s_hid[EB][HID];         // layer-1 out, reused by coord L1
    __shared__ float s_msg[EB][HID];         // messages
    __shared__ float s_rel[EB][3];
    __shared__ int   s_row[EB];
    __shared__ float s_red[EB][8];

    const int t = threadIdx.x;
    const int g = t >> 5;      // 0..7
    const int l = t & 31;      // 0..31
    const int e0 = blockIdx.x * EB;

    // ---- gather msg_in into LDS ----
    #pragma unroll
    for (int ee = 0; ee < 4; ++ee) {
        const int el  = g * 4 + ee;
        const int e   = e0 + el;
        const int row = ei[e];
        const int col = ei[E_EDGES + e];
        float4 hr = *(const float4*)(h + (size_t)row * D + l * 4);
        float4 hc = *(const float4*)(h + (size_t)col * D + l * 4);
        *(float4*)(&s_in[el][l * 4])     = hr;
        *(float4*)(&s_in[el][D + l * 4]) = hc;
        const float dx = pos[row * 3 + 0] - pos[col * 3 + 0];
        const float dy = pos[row * 3 + 1] - pos[col * 3 + 1];
        const float dz = pos[row * 3 + 2] - pos[col * 3 + 2];
        const float dist = sqrtf(dx * dx + dy * dy + dz * dz + 1e-8f);
        const float dd = dist - (10.0f / 31.0f) * (float)l;
        s_in[el][2 * D + l] = __expf(-4.805f * dd * dd);   // coeff = -0.5/(10/31)^2
        if (l == 0) {
            s_row[el] = row;
            s_rel[el][0] = dx; s_rel[el][1] = dy; s_rel[el][2] = dz;
        }
    }
    __syncthreads();

    const int cg = t & 31;
    const int eg = t >> 5;
    const int c0 = cg * 4;

    float acc[4][4];

    // ---- layer 1: [32,288] @ [288,128] + b, silu -> s_hid ----
    {
        float4 b = *(const float4*)(mb1 + c0);
        #pragma unroll
        for (int e = 0; e < 4; ++e) { acc[e][0] = b.x; acc[e][1] = b.y; acc[e][2] = b.z; acc[e][3] = b.w; }
        #pragma unroll 4
        for (int k = 0; k < 2 * D + NB; ++k) {
            float4 w = *(const float4*)(mw1 + (size_t)k * HID + c0);
            #pragma unroll
            for (int e = 0; e < 4; ++e) {
                float x = s_in[eg * 4 + e][k];
                acc[e][0] = fmaf(x, w.x, acc[e][0]);
                acc[e][1] = fmaf(x, w.y, acc[e][1]);
                acc[e][2] = fmaf(x, w.z, acc[e][2]);
                acc[e][3] = fmaf(x, w.w, acc[e][3]);
            }
        }
        #pragma unroll
        for (int e = 0; e < 4; ++e) {
            float4 o;
            o.x = silu_f(acc[e][0]); o.y = silu_f(acc[e][1]);
            o.z = silu_f(acc[e][2]); o.w = silu_f(acc[e][3]);
            *(float4*)(&s_hid[eg * 4 + e][c0]) = o;
        }
    }
    __syncthreads();

    // ---- layer 2: [32,128] @ [128,128] + b -> s_msg (messages, no act) ----
    {
        float4 b = *(const float4*)(mb2 + c0);
        #pragma unroll
        for (int e = 0; e < 4; ++e) { acc[e][0] = b.x; acc[e][1] = b.y; acc[e][2] = b.z; acc[e][3] = b.w; }
        #pragma unroll 4
        for (int k = 0; k < HID; ++k) {
            float4 w = *(const float4*)(mw2 + (size_t)k * HID + c0);
            #pragma unroll
            for (int e = 0; e < 4; ++e) {
                float x = s_hid[eg * 4 + e][k];
                acc[e][0] = fmaf(x, w.x, acc[e][0]);
                acc[e][1] = fmaf(x, w.y, acc[e][1]);
                acc[e][2] = fmaf(x, w.z, acc[e][2]);
                acc[e][3] = fmaf(x, w.w, acc[e][3]);
            }
        }
        #pragma unroll
        for (int e = 0; e < 4; ++e) {
            float4 o; o.x = acc[e][0]; o.y = acc[e][1]; o.z = acc[e][2]; o.w = acc[e][3];
            *(float4*)(&s_msg[eg * 4 + e][c0]) = o;
        }
    }
    __syncthreads();

    // ---- coord head L1: silu(messages @ cw1 + cb1) -> s_hid (reuse) ----
    {
        float4 b = *(const float4*)(cb1 + c0);
        #pragma unroll
        for (int e = 0; e < 4; ++e) { acc[e][0] = b.x; acc[e][1] = b.y; acc[e][2] = b.z; acc[e][3] = b.w; }
        #pragma unroll 4
        for (int k = 0; k < HID; ++k) {
            float4 w = *(const float4*)(cw1 + (size_t)k * HID + c0);
            #pragma unroll
            for (int e = 0; e < 4; ++e) {
                float x = s_msg[eg * 4 + e][k];
                acc[e][0] = fmaf(x, w.x, acc[e][0]);
                acc[e][1] = fmaf(x, w.y, acc[e][1]);
                acc[e][2] = fmaf(x, w.z, acc[e][2]);
                acc[e][3] = fmaf(x, w.w, acc[e][3]);
            }
        }
        #pragma unroll
        for (int e = 0; e < 4; ++e) {
            float4 o;
            o.x = silu_f(acc[e][0]); o.y = silu_f(acc[e][1]);
            o.z = silu_f(acc[e][2]); o.w = silu_f(acc[e][3]);
            *(float4*)(&s_hid[eg * 4 + e][c0]) = o;
        }
    }
    __syncthreads();

    // ---- coord head L2: per-edge scalar = s_hid[e] . cw2 + cb2 ----
    {
        const int e = t >> 3;   // 0..31
        const int p = t & 7;    // 0..7
        float sum = 0.0f;
        #pragma unroll
        for (int c = 0; c < 16; ++c)
            sum = fmaf(s_hid[e][p * 16 + c], cw2[p * 16 + c], sum);
        s_red[e][p] = sum;
    }
    __syncthreads();

    if (t < EB) {
        float m = cb2[0];
        #pragma unroll
        for (int p = 0; p < 8; ++p) m += s_red[t][p];
        const int row = s_row[t];
        atomicAdd(&aggr_coord[row * 3 + 0], s_rel[t][0] * m);
        atomicAdd(&aggr_coord[row * 3 + 1], s_rel[t][1] * m);
        atomicAdd(&aggr_coord[row * 3 + 2], s_rel[t][2] * m);
    }

    // ---- scatter messages: aggr_msgs[row] += s_msg[e] ----
    #pragma unroll
    for (int e = 0; e < 4; ++e) {
        const int el = eg * 4 + e;
        const int row = s_row[el];
        float4 mg = *(const float4*)(&s_msg[el][c0]);
        float* dst = aggr_msgs + (size_t)row * D + c0;
        atomicAdd(dst + 0, mg.x);
        atomicAdd(dst + 1, mg.y);
        atomicAdd(dst + 2, mg.z);
        atomicAdd(dst + 3, mg.w);
    }
}

// ---------------------------------------------------------------------------
// Node kernel: h_out = h + mlp([h, aggr_msgs])
// ---------------------------------------------------------------------------
__global__ __launch_bounds__(256, 2) void egnn_node(
    const float* __restrict__ h, const float* __restrict__ aggr,
    const float* __restrict__ nw1, const float* __restrict__ nb1,
    const float* __restrict__ nw2, const float* __restrict__ nb2,
    float* __restrict__ hout)
{
    __shared__ float s_in[NBK][2 * D];
    __shared__ float s_hid[NBK][HID];

    const int t = threadIdx.x;
    const int g = t >> 5;
    const int l = t & 31;
    const int n0 = blockIdx.x * NBK;

    #pragma unroll
    for (int ee = 0; ee < 4; ++ee) {
        const int nl = g * 4 + ee;
        const int n  = n0 + nl;
        float4 a = make_float4(0, 0, 0, 0), b = make_float4(0, 0, 0, 0);
        if (n < N_NODES) {
            a = *(const float4*)(h + (size_t)n * D + l * 4);
            b = *(const float4*)(aggr + (size_t)n * D + l * 4);
        }
        *(float4*)(&s_in[nl][l * 4])     = a;
        *(float4*)(&s_in[nl][D + l * 4]) = b;
    }
    __syncthreads();

    const int cg = t & 31;
    const int eg = t >> 5;
    const int c0 = cg * 4;

    float acc[4][4];
    {
        float4 b = *(const float4*)(nb1 + c0);
        #pragma unroll
        for (int e = 0; e < 4; ++e) { acc[e][0] = b.x; acc[e][1] = b.y; acc[e][2] = b.z; acc[e][3] = b.w; }
        #pragma unroll 4
        for (int k = 0; k < 2 * D; ++k) {
            float4 w = *(const float4*)(nw1 + (size_t)k * HID + c0);
            #pragma unroll
            for (int e = 0; e < 4; ++e) {
                float x = s_in[eg * 4 + e][k];
                acc[e][0] = fmaf(x, w.x, acc[e][0]);
                acc[e][1] = fmaf(x, w.y, acc[e][1]);
                acc[e][2] = fmaf(x, w.z, acc[e][2]);
                acc[e][3] = fmaf(x, w.w, acc[e][3]);
            }
        }
        #pragma unroll
        for (int e = 0; e < 4; ++e) {
            float4 o;
            o.x = silu_f(acc[e][0]); o.y = silu_f(acc[e][1]);
            o.z = silu_f(acc[e][2]); o.w = silu_f(acc[e][3]);
            *(float4*)(&s_hid[eg * 4 + e][c0]) = o;
        }
    }
    __syncthreads();
    {
        float4 b = *(const float4*)(nb2 + c0);
        #pragma unroll
        for (int e = 0; e < 4; ++e) { acc[e][0] = b.x; acc[e][1] = b.y; acc[e][2] = b.z; acc[e][3] = b.w; }
        #pragma unroll 4
        for (int k = 0; k < HID; ++k) {
            float4 w = *(const float4*)(nw2 + (size_t)k * HID + c0);
            #pragma unroll
            for (int e = 0; e < 4; ++e) {
                float x = s_hid[eg * 4 + e][k];
                acc[e][0] = fmaf(x, w.x, acc[e][0]);
                acc[e][1] = fmaf(x, w.y, acc[e][1]);
                acc[e][2] = fmaf(x, w.z, acc[e][2]);
                acc[e][3] = fmaf(x, w.w, acc[e][3]);
            }
        }
        #pragma unroll
        for (int e = 0; e < 4; ++e) {
            const int n = n0 + eg * 4 + e;
            if (n < N_NODES) {
                const float4 hv = *(const float4*)(h + (size_t)n * D + c0);
                float4 o;
                o.x = hv.x + acc[e][0]; o.y = hv.y + acc[e][1];
                o.z = hv.z + acc[e][2]; o.w = hv.w + acc[e][3];
                *(float4*)(hout + (size_t)n * D + c0) = o;
            }
        }
    }
}

__global__ void egnn_pos(const float* __restrict__ pos,
                         const float* __restrict__ aggr_coord,
                         float* __restrict__ pout)
{
    int i = blockIdx.x * 256 + threadIdx.x;
    if (i < N_NODES * 3) pout[i] = pos[i] + aggr_coord[i];
}

extern "C" void kernel_launch(void* const* d_in, const int* in_sizes, int n_in,
                              void* d_out, int out_size, void* d_ws, size_t ws_size,
                              hipStream_t stream)
{
    const float* h   = (const float*)d_in[0];
    const float* pos = (const float*)d_in[1];
    const int*   ei  = (const int*)d_in[2];
    const float* mw1 = (const float*)d_in[3];
    const float* mb1 = (const float*)d_in[4];
    const float* mw2 = (const float*)d_in[5];
    const float* mb2 = (const float*)d_in[6];
    const float* nw1 = (const float*)d_in[7];
    const float* nb1 = (const float*)d_in[8];
    const float* nw2 = (const float*)d_in[9];
    const float* nb2 = (const float*)d_in[10];
    const float* cw1 = (const float*)d_in[11];
    const float* cb1 = (const float*)d_in[12];
    const float* cw2 = (const float*)d_in[13];
    const float* cb2 = (const float*)d_in[14];

    float* out        = (float*)d_out;
    float* aggr_msgs  = (float*)d_ws;                       // N*128 f32
    float* aggr_coord = aggr_msgs + (size_t)N_NODES * D;    // N*3  f32

    hipMemsetAsync(d_ws, 0, (size_t)(N_NODES * D + N_NODES * 3) * sizeof(float), stream);

    egnn_edge<<<E_EDGES / EB, 256, 0, stream>>>(
        h, pos, ei, mw1, mb1, mw2, mb2, cw1, cb1, cw2, cb2,
        aggr_msgs, aggr_coord);

    egnn_node<<<(N_NODES + NBK - 1) / NBK, 256, 0, stream>>>(
        h, aggr_msgs, nw1, nb1, nw2, nb2, out);

    egnn_pos<<<(N_NODES * 3 + 255) / 256, 256, 0, stream>>>(
        pos, aggr_coord, out + (size_t)N_NODES * D);
}

// Round 3
// 602.183 us; speedup vs baseline: 4.3335x; 4.3335x over previous
//
#include <hip/hip_runtime.h>
#include <math.h>

#define N_NODES 50000
#define E_EDGES 800000
#define D 128
#define HID 128
#define NB 32

typedef __attribute__((ext_vector_type(8))) short bf16x8;
typedef __attribute__((ext_vector_type(4))) float f32x4;

// packed-weight fragment-group bases (units of 64-lane fragment groups;
// one kstep = 8 groups). pack_w stores group bid = ksg*8+nf at slot bid*64+lane.
#define MW1F 0        // ksg 0..8   (K=288)
#define MW2F 72       // ksg 9..12  (K=128)
#define CW1F 104      // ksg 13..16 (K=128)
#define NW1F 136      // ksg 17..24 (K=256)
#define NW2F 200      // ksg 25..28 (K=128)
#define TOT_KSTEPS 29

__device__ __forceinline__ short f2bf(float f) {
    union { float f; unsigned u; } v; v.f = f;
    unsigned r = v.u + 0x7fffu + ((v.u >> 16) & 1u);
    return (short)(r >> 16);
}
__device__ __forceinline__ float silu_f(float x) { return x / (1.0f + __expf(-x)); }
__device__ __forceinline__ f32x4 splat4(float b) { f32x4 v = {b, b, b, b}; return v; }

// ---------------------------------------------------------------------------
// Pack fp32 weights [K,128] into MFMA B-fragment bf16 layout:
// frag (kstep,nfrag): lane l holds B[kstep*32 + (l>>4)*8 + j][nfrag*16 + (l&15)]
// ---------------------------------------------------------------------------
__global__ void pack_w(const float* __restrict__ mw1, const float* __restrict__ mw2,
                       const float* __restrict__ cw1, const float* __restrict__ nw1,
                       const float* __restrict__ nw2, short* __restrict__ wp)
{
    const int bid = blockIdx.x;         // 29*8 = 232 blocks
    const int ks = bid >> 3, nf = bid & 7;
    const int l = threadIdx.x;          // 64 threads
    const float* src; int k0;
    if (ks < 9)       { src = mw1; k0 = ks; }
    else if (ks < 13) { src = mw2; k0 = ks - 9; }
    else if (ks < 17) { src = cw1; k0 = ks - 13; }
    else if (ks < 25) { src = nw1; k0 = ks - 17; }
    else              { src = nw2; k0 = ks - 25; }
    bf16x8 pv;
    #pragma unroll
    for (int j = 0; j < 8; ++j)
        pv[j] = f2bf(src[(size_t)(k0 * 32 + (l >> 4) * 8 + j) * 128 + nf * 16 + (l & 15)]);
    *((bf16x8*)wp + (size_t)bid * 64 + l) = pv;
}

// GEMM inner: 2 M-frags (rows 0..15, 16..31) x 8 N-frags, K = KSTEPS*32.
// A from swizzled LDS (row stride STRIDE bytes), B from packed global.
#define GEMM2(KSTEPS, STRIDE, WBASE)                                           \
    _Pragma("unroll")                                                          \
    for (int ks = 0; ks < KSTEPS; ++ks) {                                      \
        const int kd = ks * 32 + ag * 8;                                       \
        int b0 = ar * STRIDE + kd * 2;        b0 ^= (ar & 7) << 4;             \
        int b1 = (16 + ar) * STRIDE + kd * 2; b1 ^= (ar & 7) << 4;             \
        bf16x8 a0 = *(const bf16x8*)(sx + b0);                                 \
        bf16x8 a1 = *(const bf16x8*)(sx + b1);                                 \
        const bf16x8* bw = wpv + (size_t)(WBASE + ks * 8) * 64 + l;            \
        _Pragma("unroll")                                                      \
        for (int n = 0; n < 8; ++n) {                                          \
            bf16x8 bb = bw[n * 64];                                            \
            acc0[n] = __builtin_amdgcn_mfma_f32_16x16x32_bf16(a0, bb, acc0[n], 0, 0, 0); \
            acc1[n] = __builtin_amdgcn_mfma_f32_16x16x32_bf16(a1, bb, acc1[n], 0, 0, 0); \
        }                                                                      \
    }

// ---------------------------------------------------------------------------
// Edge kernel: 128 threads = 2 independent waves, 32 edges per wave.
// No __syncthreads — per-wave LDS regions, in-order per-wave LDS pipe.
// ---------------------------------------------------------------------------
__global__ __launch_bounds__(128, 2) void egnn_edge(
    const float* __restrict__ h, const float* __restrict__ pos,
    const int* __restrict__ ei,
    const float* __restrict__ mb1, const float* __restrict__ mb2,
    const float* __restrict__ cb1, const float* __restrict__ cw2,
    const float* __restrict__ cb2, const short* __restrict__ wp,
    float* __restrict__ aggr_msgs, float* __restrict__ aggr_coord)
{
    __shared__ char sm[2][18432];          // per-wave: X1 [32][288] bf16, reused for H1/MSG [32][128]
    __shared__ int   s_rowm[2][32];
    __shared__ float s_relm[2][32][3];

    const int t = threadIdx.x;
    const int w = t >> 6;
    const int l = t & 63;
    char* sx = sm[w];
    const bf16x8* wpv = (const bf16x8*)wp;
    const int e0 = blockIdx.x * 64 + w * 32;

    // ---- gather X1 = [h[row] | h[col] | gauss(dist)] as bf16, swizzled ----
    {
        const int e_loc = l & 31, half = l >> 5;
        const int ge = e0 + e_loc;
        const int row = ei[ge], col = ei[E_EDGES + ge];
        const float dx = pos[row * 3 + 0] - pos[col * 3 + 0];
        const float dy = pos[row * 3 + 1] - pos[col * 3 + 1];
        const float dz = pos[row * 3 + 2] - pos[col * 3 + 2];
        const float dist = sqrtf(dx * dx + dy * dy + dz * dz + 1e-8f);
        if (half == 0) {
            s_rowm[w][e_loc] = row;
            s_relm[w][e_loc][0] = dx; s_relm[w][e_loc][1] = dy; s_relm[w][e_loc][2] = dz;
        }
        const float GS = 10.0f / 31.0f;
        const float GC = -0.5f / (GS * GS);
        const float* hrow = h + (size_t)row * D;
        const float* hcol = h + (size_t)col * D;
        #pragma unroll
        for (int c = 0; c < 18; ++c) {
            const int k0 = half * 144 + c * 8;
            float v[8];
            if (k0 < 256) {
                const float* src = (k0 < 128) ? (hrow + k0) : (hcol + (k0 - 128));
                float4 va = *(const float4*)src;
                float4 vb = *(const float4*)(src + 4);
                v[0] = va.x; v[1] = va.y; v[2] = va.z; v[3] = va.w;
                v[4] = vb.x; v[5] = vb.y; v[6] = vb.z; v[7] = vb.w;
            } else {
                #pragma unroll
                for (int j = 0; j < 8; ++j) {
                    float dd = dist - (float)(k0 - 256 + j) * GS;
                    v[j] = __expf(GC * dd * dd);
                }
            }
            bf16x8 sv;
            #pragma unroll
            for (int j = 0; j < 8; ++j) sv[j] = f2bf(v[j]);
            int byte = e_loc * 576 + k0 * 2;
            byte ^= (e_loc & 7) << 4;
            *(bf16x8*)(sx + byte) = sv;
        }
    }
    asm volatile("s_waitcnt lgkmcnt(0)" ::: "memory");

    const int ar = l & 15, ag = l >> 4;
    f32x4 acc0[8], acc1[8];

    // ---- L1: X1[32,288] @ mw1 -> silu -> H1 ----
    #pragma unroll
    for (int n = 0; n < 8; ++n) {
        float b = mb1[n * 16 + ar];
        acc0[n] = splat4(b); acc1[n] = splat4(b);
    }
    GEMM2(9, 576, MW1F)

    #pragma unroll
    for (int m = 0; m < 2; ++m)
        #pragma unroll
        for (int n = 0; n < 8; ++n)
            #pragma unroll
            for (int r = 0; r < 4; ++r) {
                float x = (m == 0) ? acc0[n][r] : acc1[n][r];
                const int rw = m * 16 + ag * 4 + r;
                const int cl = n * 16 + ar;
                int byte = rw * 256 + cl * 2;
                byte ^= (rw & 7) << 4;
                *(short*)(sx + byte) = f2bf(silu_f(x));
            }
    asm volatile("s_waitcnt lgkmcnt(0)" ::: "memory");

    // ---- L2: H1 @ mw2 -> MSG (fp32 in acc) ----
    #pragma unroll
    for (int n = 0; n < 8; ++n) {
        float b = mb2[n * 16 + ar];
        acc0[n] = splat4(b); acc1[n] = splat4(b);
    }
    GEMM2(4, 256, MW2F)

    int grows[2][4];
    #pragma unroll
    for (int m = 0; m < 2; ++m)
        #pragma unroll
        for (int r = 0; r < 4; ++r)
            grows[m][r] = s_rowm[w][m * 16 + ag * 4 + r];

    // store MSG bf16 to LDS (C1 input) + atomic scatter from fp32
    #pragma unroll
    for (int m = 0; m < 2; ++m)
        #pragma unroll
        for (int n = 0; n < 8; ++n)
            #pragma unroll
            for (int r = 0; r < 4; ++r) {
                float x = (m == 0) ? acc0[n][r] : acc1[n][r];
                const int rw = m * 16 + ag * 4 + r;
                const int cl = n * 16 + ar;
                int byte = rw * 256 + cl * 2;
                byte ^= (rw & 7) << 4;
                *(short*)(sx + byte) = f2bf(x);
                atomicAdd(&aggr_msgs[(size_t)grows[m][r] * D + cl], x);
            }
    asm volatile("s_waitcnt lgkmcnt(0)" ::: "memory");

    // ---- C1: MSG @ cw1 -> CH (silu applied in C2 dot) ----
    #pragma unroll
    for (int n = 0; n < 8; ++n) {
        float b = cb1[n * 16 + ar];
        acc0[n] = splat4(b); acc1[n] = splat4(b);
    }
    GEMM2(4, 256, CW1F)

    // ---- C2: per-edge scalar dot + coord scatter ----
    float cw2v[8];
    #pragma unroll
    for (int n = 0; n < 8; ++n) cw2v[n] = cw2[n * 16 + ar];
    float p0[4], p1[4];
    #pragma unroll
    for (int r = 0; r < 4; ++r) {
        float s0 = 0.f, s1 = 0.f;
        #pragma unroll
        for (int n = 0; n < 8; ++n) {
            s0 += silu_f(acc0[n][r]) * cw2v[n];
            s1 += silu_f(acc1[n][r]) * cw2v[n];
        }
        p0[r] = s0; p1[r] = s1;
    }
    #pragma unroll
    for (int off = 1; off < 16; off <<= 1) {
        #pragma unroll
        for (int r = 0; r < 4; ++r) {
            p0[r] += __shfl_xor(p0[r], off);
            p1[r] += __shfl_xor(p1[r], off);
        }
    }
    if (ar == 0) {
        const float cb = cb2[0];
        #pragma unroll
        for (int m = 0; m < 2; ++m)
            #pragma unroll
            for (int r = 0; r < 4; ++r) {
                const int el = m * 16 + ag * 4 + r;
                const float mm = ((m == 0) ? p0[r] : p1[r]) + cb;
                const int gr = grows[m][r];
                atomicAdd(&aggr_coord[gr * 3 + 0], s_relm[w][el][0] * mm);
                atomicAdd(&aggr_coord[gr * 3 + 1], s_relm[w][el][1] * mm);
                atomicAdd(&aggr_coord[gr * 3 + 2], s_relm[w][el][2] * mm);
            }
    }
}

// ---------------------------------------------------------------------------
// Node kernel: h_out = h + mlp([h, aggr_msgs]); 2 waves x 32 nodes.
// ---------------------------------------------------------------------------
__global__ __launch_bounds__(128, 2) void egnn_node(
    const float* __restrict__ h, const float* __restrict__ aggr,
    const float* __restrict__ nb1, const float* __restrict__ nb2,
    const short* __restrict__ wp, float* __restrict__ out)
{
    __shared__ char sm[2][16384];          // per-wave X [32][256] bf16, reused for H [32][128]
    const int t = threadIdx.x, w = t >> 6, l = t & 63;
    char* sx = sm[w];
    const bf16x8* wpv = (const bf16x8*)wp;
    const int n0 = blockIdx.x * 64 + w * 32;

    {
        const int n_loc = l & 31, half = l >> 5;
        int gn = n0 + n_loc; if (gn >= N_NODES) gn = N_NODES - 1;
        const float* src = (half == 0) ? (h + (size_t)gn * D) : (aggr + (size_t)gn * D);
        #pragma unroll
        for (int c = 0; c < 16; ++c) {
            float4 va = *(const float4*)(src + c * 8);
            float4 vb = *(const float4*)(src + c * 8 + 4);
            float v[8] = {va.x, va.y, va.z, va.w, vb.x, vb.y, vb.z, vb.w};
            bf16x8 sv;
            #pragma unroll
            for (int j = 0; j < 8; ++j) sv[j] = f2bf(v[j]);
            int byte = n_loc * 512 + (half * 128 + c * 8) * 2;
            byte ^= (n_loc & 7) << 4;
            *(bf16x8*)(sx + byte) = sv;
        }
    }
    asm volatile("s_waitcnt lgkmcnt(0)" ::: "memory");

    const int ar = l & 15, ag = l >> 4;
    f32x4 acc0[8], acc1[8];

    #pragma unroll
    for (int n = 0; n < 8; ++n) {
        float b = nb1[n * 16 + ar];
        acc0[n] = splat4(b); acc1[n] = splat4(b);
    }
    GEMM2(8, 512, NW1F)

    #pragma unroll
    for (int m = 0; m < 2; ++m)
        #pragma unroll
        for (int n = 0; n < 8; ++n)
            #pragma unroll
            for (int r = 0; r < 4; ++r) {
                float x = (m == 0) ? acc0[n][r] : acc1[n][r];
                const int rw = m * 16 + ag * 4 + r;
                const int cl = n * 16 + ar;
                int byte = rw * 256 + cl * 2;
                byte ^= (rw & 7) << 4;
                *(short*)(sx + byte) = f2bf(silu_f(x));
            }
    asm volatile("s_waitcnt lgkmcnt(0)" ::: "memory");

    #pragma unroll
    for (int n = 0; n < 8; ++n) {
        float b = nb2[n * 16 + ar];
        acc0[n] = splat4(b); acc1[n] = splat4(b);
    }
    GEMM2(4, 256, NW2F)

    #pragma unroll
    for (int m = 0; m < 2; ++m)
        #pragma unroll
        for (int n = 0; n < 8; ++n)
            #pragma unroll
            for (int r = 0; r < 4; ++r) {
                const int rw = m * 16 + ag * 4 + r;
                const int gnode = n0 + rw;
                if (gnode < N_NODES) {
                    const int cl = n * 16 + ar;
                    float x = (m == 0) ? acc0[n][r] : acc1[n][r];
                    out[(size_t)gnode * D + cl] = h[(size_t)gnode * D + cl] + x;
                }
            }
}

__global__ void egnn_pos(const float* __restrict__ pos,
                         const float* __restrict__ aggr_coord,
                         float* __restrict__ pout)
{
    int i = blockIdx.x * 256 + threadIdx.x;
    if (i < N_NODES * 3) pout[i] = pos[i] + aggr_coord[i];
}

extern "C" void kernel_launch(void* const* d_in, const int* in_sizes, int n_in,
                              void* d_out, int out_size, void* d_ws, size_t ws_size,
                              hipStream_t stream)
{
    const float* h   = (const float*)d_in[0];
    const float* pos = (const float*)d_in[1];
    const int*   ei  = (const int*)d_in[2];
    const float* mw1 = (const float*)d_in[3];
    const float* mb1 = (const float*)d_in[4];
    const float* mw2 = (const float*)d_in[5];
    const float* mb2 = (const float*)d_in[6];
    const float* nw1 = (const float*)d_in[7];
    const float* nb1 = (const float*)d_in[8];
    const float* nw2 = (const float*)d_in[9];
    const float* nb2 = (const float*)d_in[10];
    const float* cw1 = (const float*)d_in[11];
    const float* cb1 = (const float*)d_in[12];
    const float* cw2 = (const float*)d_in[13];
    const float* cb2 = (const float*)d_in[14];

    float* out        = (float*)d_out;
    float* aggr_msgs  = (float*)d_ws;                         // N*128 f32
    float* aggr_coord = aggr_msgs + (size_t)N_NODES * D;      // N*3   f32
    short* wpack      = (short*)(aggr_coord + (size_t)N_NODES * 3);  // 29*8*64*8 bf16 (232KB)

    hipMemsetAsync(d_ws, 0, (size_t)(N_NODES * D + N_NODES * 3) * sizeof(float), stream);

    pack_w<<<TOT_KSTEPS * 8, 64, 0, stream>>>(mw1, mw2, cw1, nw1, nw2, wpack);

    egnn_edge<<<E_EDGES / 64, 128, 0, stream>>>(
        h, pos, ei, mb1, mb2, cb1, cw2, cb2, wpack, aggr_msgs, aggr_coord);

    egnn_node<<<(N_NODES + 63) / 64, 128, 0, stream>>>(
        h, aggr_msgs, nb1, nb2, wpack, out);

    egnn_pos<<<(N_NODES * 3 + 255) / 256, 256, 0, stream>>>(
        pos, aggr_coord, out + (size_t)N_NODES * D);
}